// Round 1
// baseline (99.912 us; speedup 1.0000x reference)
//
#include <hip/hip_runtime.h>
#include <hip/hip_bf16.h>
#include <cstdint>

#define NPTS 65536
#define CCH  1024
#define BSEG 256
#define KSLOT 512

// monotonic float<->int key mapping (no NaNs in input)
__device__ __forceinline__ int fkey(float f) {
  int i = __float_as_int(f);
  return i >= 0 ? i : (i ^ 0x7FFFFFFF);
}
__device__ __forceinline__ float fdec(int k) {
  int i = k >= 0 ? k : (k ^ 0x7FFFFFFF);
  return __int_as_float(i);
}
#define NEGKEY ((int)0x807FFFFF)   // fkey(-inf)

__device__ __forceinline__ float4 max4(float4 a, float4 b) {
  return make_float4(fmaxf(a.x, b.x), fmaxf(a.y, b.y), fmaxf(a.z, b.z), fmaxf(a.w, b.w));
}

__global__ __launch_bounds__(256) void init_keys_k(int* __restrict__ keys) {
  keys[blockIdx.x * 256 + threadIdx.x] = NEGKEY;
}

// 1024 blocks x 256 threads; each block streams 64 rows, float4 per lane.
__global__ __launch_bounds__(256) void segmax_k(const float* __restrict__ feat,
                                                const int* __restrict__ offsets,
                                                int* __restrict__ keys) {
  int t = threadIdx.x;
  int col = t << 2;
  int row0 = blockIdx.x * 64;
  int row_end = row0 + 64;
  // first seg with offsets[seg] > row0
  int lo = 0, hi = BSEG - 1;
  while (lo < hi) { int mid = (lo + hi) >> 1; if (offsets[mid] > row0) hi = mid; else lo = mid + 1; }
  int seg = lo;
  int end = offsets[seg];
  const float NI = __int_as_float(0xFF800000);
  float4 m = make_float4(NI, NI, NI, NI);
  bool dirty = false;
  int r = row0;
  while (r < row_end) {
    while (r >= end) {
      if (dirty) {
        int* kp = keys + seg * CCH + col;
        atomicMax(kp + 0, fkey(m.x));
        atomicMax(kp + 1, fkey(m.y));
        atomicMax(kp + 2, fkey(m.z));
        atomicMax(kp + 3, fkey(m.w));
        m = make_float4(NI, NI, NI, NI);
        dirty = false;
      }
      ++seg;
      end = offsets[seg];
    }
    int stop = min(row_end, end);
    const float* p = feat + (size_t)r * CCH + col;
    for (; r + 4 <= stop; r += 4) {
      float4 v0 = *(const float4*)(p);
      float4 v1 = *(const float4*)(p + CCH);
      float4 v2 = *(const float4*)(p + 2 * CCH);
      float4 v3 = *(const float4*)(p + 3 * CCH);
      p += 4 * CCH;
      m = max4(m, max4(max4(v0, v1), max4(v2, v3)));
    }
    for (; r < stop; ++r) {
      float4 v = *(const float4*)(p);
      p += CCH;
      m = max4(m, v);
    }
    dirty = true;
  }
  if (dirty) {
    int* kp = keys + seg * CCH + col;
    atomicMax(kp + 0, fkey(m.x));
    atomicMax(kp + 1, fkey(m.y));
    atomicMax(kp + 2, fkey(m.z));
    atomicMax(kp + 3, fkey(m.w));
  }
}

__global__ __launch_bounds__(256) void finalize_k(const int* __restrict__ keys,
                                                  const int* __restrict__ offsets,
                                                  float* __restrict__ outf) {
  int idx = blockIdx.x * 256 + threadIdx.x;
  int b = idx >> 10;
  int len = offsets[b] - (b ? offsets[b - 1] : 0);
  float f = fdec(keys[idx]);
  if (len < KSLOT) f = fmaxf(f, 0.0f);
  outf[idx] = f;
}

// out[M=256, N=512] partials = A[256,K] @ W[N,K]^T (W row for col c: c<nlo ? Wlo[c] : Whi[c-nlo])
// 64x64 tile, 4x4 per thread, BK=32, K split across grid.z into `part` chunks of 256*512 floats.
__global__ __launch_bounds__(256) void gemm_nt_part(
    const float* __restrict__ A, int lda,
    const float* __restrict__ Wlo, const float* __restrict__ Whi, int nlo, int ldw,
    float* __restrict__ part, int Ktot, int steps_per_chunk) {
  __shared__ float As[32][68];
  __shared__ float Ws[32][68];
  int bx = blockIdx.x, by = blockIdx.y, bz = blockIdx.z;
  int t = threadIdx.x;
  int tx = t & 15, ty = t >> 4;
  int steps_total = Ktot >> 5;
  int step0 = bz * steps_per_chunk;
  int nsteps = min(steps_per_chunk, steps_total - step0);
  int lr = t >> 3;          // 0..31
  int lk = (t & 7) << 2;    // 0,4,...,28
  const float* Arow0 = A + (size_t)(by * 64 + lr) * lda + lk;
  const float* Arow1 = Arow0 + (size_t)32 * lda;
  int c0 = bx * 64 + lr;
  int c1 = c0 + 32;
  const float* Wrow0 = (c0 < nlo ? Wlo + (size_t)c0 * ldw : Whi + (size_t)(c0 - nlo) * ldw) + lk;
  const float* Wrow1 = (c1 < nlo ? Wlo + (size_t)c1 * ldw : Whi + (size_t)(c1 - nlo) * ldw) + lk;
  float acc[4][4] = {};
  for (int s = 0; s < nsteps; ++s) {
    int k0 = (step0 + s) << 5;
    float4 a0 = *(const float4*)(Arow0 + k0);
    float4 a1 = *(const float4*)(Arow1 + k0);
    float4 w0 = *(const float4*)(Wrow0 + k0);
    float4 w1 = *(const float4*)(Wrow1 + k0);
    __syncthreads();
    As[lk + 0][lr] = a0.x; As[lk + 1][lr] = a0.y; As[lk + 2][lr] = a0.z; As[lk + 3][lr] = a0.w;
    As[lk + 0][lr + 32] = a1.x; As[lk + 1][lr + 32] = a1.y; As[lk + 2][lr + 32] = a1.z; As[lk + 3][lr + 32] = a1.w;
    Ws[lk + 0][lr] = w0.x; Ws[lk + 1][lr] = w0.y; Ws[lk + 2][lr] = w0.z; Ws[lk + 3][lr] = w0.w;
    Ws[lk + 0][lr + 32] = w1.x; Ws[lk + 1][lr + 32] = w1.y; Ws[lk + 2][lr + 32] = w1.z; Ws[lk + 3][lr + 32] = w1.w;
    __syncthreads();
#pragma unroll
    for (int kk = 0; kk < 32; ++kk) {
      float4 av = *(const float4*)&As[kk][ty << 2];
      float4 wv = *(const float4*)&Ws[kk][tx << 2];
      acc[0][0] += av.x * wv.x; acc[0][1] += av.x * wv.y; acc[0][2] += av.x * wv.z; acc[0][3] += av.x * wv.w;
      acc[1][0] += av.y * wv.x; acc[1][1] += av.y * wv.y; acc[1][2] += av.y * wv.z; acc[1][3] += av.y * wv.w;
      acc[2][0] += av.z * wv.x; acc[2][1] += av.z * wv.y; acc[2][2] += av.z * wv.z; acc[2][3] += av.z * wv.w;
      acc[3][0] += av.w * wv.x; acc[3][1] += av.w * wv.y; acc[3][2] += av.w * wv.z; acc[3][3] += av.w * wv.w;
    }
  }
  float* op = part + (size_t)bz * 131072 + (size_t)(by * 64 + (ty << 2)) * 512 + bx * 64 + (tx << 2);
#pragma unroll
  for (int i = 0; i < 4; ++i) {
    *(float4*)(op + (size_t)i * 512) = make_float4(acc[i][0], acc[i][1], acc[i][2], acc[i][3]);
  }
}

// per-row: sum 4 K-partials + b1 -> LN(512) -> ReLU -> x[:,0:512]; info layer -> x[:,512:544]
__global__ __launch_bounds__(256) void ln1_x_k(
    const float* __restrict__ part1, const float* __restrict__ b1,
    const float* __restrict__ g, const float* __restrict__ be,
    const float* __restrict__ info, const float* __restrict__ Wi, const float* __restrict__ bi,
    float* __restrict__ x) {
  int b = blockIdx.x, t = threadIdx.x;
  int wv = t >> 6, ln = t & 63;
  __shared__ float red[2][4];
  __shared__ float stats[2];
  const float* p = part1 + (size_t)b * 512;
  float z0 = b1[t] + p[t] + p[131072 + t] + p[262144 + t] + p[393216 + t];
  int c1 = t + 256;
  float z1 = b1[c1] + p[c1] + p[131072 + c1] + p[262144 + c1] + p[393216 + c1];
  float s = z0 + z1, q = z0 * z0 + z1 * z1;
#pragma unroll
  for (int o = 32; o; o >>= 1) { s += __shfl_down(s, o); q += __shfl_down(q, o); }
  if (ln == 0) { red[0][wv] = s; red[1][wv] = q; }
  __syncthreads();
  if (t == 0) {
    float S = red[0][0] + red[0][1] + red[0][2] + red[0][3];
    float Q = red[1][0] + red[1][1] + red[1][2] + red[1][3];
    float mean = S * (1.f / 512.f);
    float var = Q * (1.f / 512.f) - mean * mean;
    stats[0] = mean; stats[1] = rsqrtf(var + 1e-5f);
  }
  __syncthreads();
  float mean = stats[0], rstd = stats[1];
  x[b * 544 + t]  = fmaxf((z0 - mean) * rstd * g[t]  + be[t],  0.f);
  x[b * 544 + c1] = fmaxf((z1 - mean) * rstd * g[c1] + be[c1], 0.f);
  if (t < 32) {
    float i0 = info[b * 3], i1 = info[b * 3 + 1], i2 = info[b * 3 + 2];
    x[b * 544 + 512 + t] = bi[t] + Wi[t * 3] * i0 + Wi[t * 3 + 1] * i1 + Wi[t * 3 + 2] * i2;
  }
}

// per-row: sum 2 K-partials + bias -> LN(256) -> ReLU for both heads, then 6+18 dot products.
__global__ __launch_bounds__(256) void heads_k(
    const float* __restrict__ part2,
    const float* __restrict__ ba1, const float* __restrict__ ga, const float* __restrict__ bea,
    const float* __restrict__ Wa2, const float* __restrict__ ba2,
    const float* __restrict__ bo1, const float* __restrict__ go, const float* __restrict__ beo,
    const float* __restrict__ Wo2, const float* __restrict__ bo2,
    float* __restrict__ outp) {
  int b = blockIdx.x, t = threadIdx.x;
  int wv = t >> 6, ln = t & 63;
  __shared__ float h[512];
  __shared__ float red[4][4];
  __shared__ float stats[4];
  const float* p0 = part2 + (size_t)b * 512;
  const float* p1 = p0 + 131072;
  float za = ba1[t] + p0[t] + p1[t];
  float zo = bo1[t] + p0[256 + t] + p1[256 + t];
  float sa = za, qa = za * za, so = zo, qo = zo * zo;
#pragma unroll
  for (int o = 32; o; o >>= 1) {
    sa += __shfl_down(sa, o); qa += __shfl_down(qa, o);
    so += __shfl_down(so, o); qo += __shfl_down(qo, o);
  }
  if (ln == 0) { red[wv][0] = sa; red[wv][1] = qa; red[wv][2] = so; red[wv][3] = qo; }
  __syncthreads();
  if (t == 0) {
    float Sa = red[0][0] + red[1][0] + red[2][0] + red[3][0];
    float Qa = red[0][1] + red[1][1] + red[2][1] + red[3][1];
    float So = red[0][2] + red[1][2] + red[2][2] + red[3][2];
    float Qo = red[0][3] + red[1][3] + red[2][3] + red[3][3];
    float ma = Sa * (1.f / 256.f), va = Qa * (1.f / 256.f) - ma * ma;
    float mo = So * (1.f / 256.f), vo = Qo * (1.f / 256.f) - mo * mo;
    stats[0] = ma; stats[1] = rsqrtf(va + 1e-5f);
    stats[2] = mo; stats[3] = rsqrtf(vo + 1e-5f);
  }
  __syncthreads();
  h[t]       = fmaxf((za - stats[0]) * stats[1] * ga[t] + bea[t], 0.f);
  h[256 + t] = fmaxf((zo - stats[2]) * stats[3] * go[t] + beo[t], 0.f);
  __syncthreads();
  const float* hh = (wv == 0) ? h : (h + 256);
  const float* W2 = (wv == 0) ? Wa2 : Wo2;
  const float* b2 = (wv == 0) ? ba2 : bo2;
  int o0 = (wv == 0) ? 0 : (wv - 1) * 6;
  int base = (wv == 0) ? (262144 + b * 6) : (263680 + b * 18);
  float h0 = hh[ln], h1 = hh[64 + ln], h2v = hh[128 + ln], h3 = hh[192 + ln];
#pragma unroll
  for (int oo = 0; oo < 6; ++oo) {
    int o = o0 + oo;
    const float* w = W2 + o * 256;
    float pr = h0 * w[ln] + h1 * w[64 + ln] + h2v * w[128 + ln] + h3 * w[192 + ln];
#pragma unroll
    for (int d = 32; d; d >>= 1) pr += __shfl_down(pr, d);
    if (ln == 0) outp[base + o] = pr + b2[o];
  }
}

extern "C" void kernel_launch(void* const* d_in, const int* in_sizes, int n_in,
                              void* d_out, int out_size, void* d_ws, size_t ws_size,
                              hipStream_t stream) {
  const float* feat   = (const float*)d_in[0];
  const float* info   = (const float*)d_in[1];
  const int*   offs   = (const int*)d_in[2];
  const float* W1     = (const float*)d_in[3];
  const float* b1     = (const float*)d_in[4];
  const float* ln1_g  = (const float*)d_in[5];
  const float* ln1_b  = (const float*)d_in[6];
  const float* Wi     = (const float*)d_in[7];
  const float* bi     = (const float*)d_in[8];
  const float* Wa1    = (const float*)d_in[9];
  const float* ba1    = (const float*)d_in[10];
  const float* lna_g  = (const float*)d_in[11];
  const float* lna_b  = (const float*)d_in[12];
  const float* Wa2    = (const float*)d_in[13];
  const float* ba2    = (const float*)d_in[14];
  const float* Wo1    = (const float*)d_in[15];
  const float* bo1    = (const float*)d_in[16];
  const float* lno_g  = (const float*)d_in[17];
  const float* lno_b  = (const float*)d_in[18];
  const float* Wo2    = (const float*)d_in[19];
  const float* bo2    = (const float*)d_in[20];

  char* ws = (char*)d_ws;
  int*   keys  = (int*)ws;                                 // 1 MB  (256*1024 int)
  float* part1 = (float*)(ws + (1u << 20));                // 2 MB  (4*256*512 f32)
  float* xbuf  = (float*)(ws + 3u * (1u << 20));           // 557 KB (256*544 f32)
  float* part2 = (float*)(ws + 3u * (1u << 20) + 655360u); // 1 MB  (2*256*512 f32)
  float* features = (float*)d_out;   // [0, 262144)
  float* outp = (float*)d_out;       // pred at 262144, offset at 263680

  init_keys_k<<<dim3(1024), dim3(256), 0, stream>>>(keys);
  segmax_k<<<dim3(1024), dim3(256), 0, stream>>>(feat, offs, keys);
  finalize_k<<<dim3(1024), dim3(256), 0, stream>>>(keys, offs, features);
  // GEMM1: features(256x1024) @ W1^T -> part1 (K=1024, 4 chunks of 8 steps)
  gemm_nt_part<<<dim3(8, 4, 4), dim3(256), 0, stream>>>(
      features, 1024, W1, W1, 512, 1024, part1, 1024, 8);
  ln1_x_k<<<dim3(256), dim3(256), 0, stream>>>(part1, b1, ln1_g, ln1_b, info, Wi, bi, xbuf);
  // GEMM2: x(256x544) @ [Wa1;Wo1]^T -> part2 (K=544 -> 17 steps: 9+8)
  gemm_nt_part<<<dim3(8, 4, 2), dim3(256), 0, stream>>>(
      xbuf, 544, Wa1, Wo1, 256, 544, part2, 544, 9);
  heads_k<<<dim3(256), dim3(256), 0, stream>>>(
      part2, ba1, lna_g, lna_b, Wa2, ba2, bo1, lno_g, lno_b, Wo2, bo2, outp);
}